// Round 1
// 2409.668 us; speedup vs baseline: 2.1850x; 2.1850x over previous
//
#include <hip/hip_runtime.h>
#include <stdint.h>

typedef __attribute__((ext_vector_type(8))) short bf16x8;
typedef __attribute__((ext_vector_type(4))) float f32x4;

#define DEV __device__ __forceinline__

DEV unsigned short f2bf(float f) {
    unsigned b = __float_as_uint(f);
    unsigned r = (b + 0x7fffu + ((b >> 16) & 1u)) >> 16;   // RNE
    return (unsigned short)r;
}
DEV unsigned pack2(float a, float b) {
    return (unsigned)f2bf(a) | ((unsigned)f2bf(b) << 16);
}
DEV float sigm(float x) { return 1.f / (1.f + __expf(-x)); }
DEV float tanh_f(float x) {
    float t = __expf(-2.f * fabsf(x));
    float r = (1.f - t) / (1.f + t);
    return copysignf(r, x);
}

// ws layout (bytes)
// [0, 32768):       u64 hglob[2][2048]  tagged h exchange (tag:32 | 2xbf16:32)
#define OFF_XE    65536      // 2 MB bf16 Xe[4096][256]
#define OFF_XG    2162688    // 8 MB bf16 xg[4096][1024]
#define OFF_HS    10551296   // 2 MB bf16 hs[4096][256]

// ---------------------------------------------------------------------------
// Embedding gather + fp32->bf16: Xe[row][0:200] = bf16(emb[x[row]]), pad 0
// ---------------------------------------------------------------------------
__global__ __launch_bounds__(256) void k_embed(const int* __restrict__ x,
                                               const float* __restrict__ emb,
                                               unsigned short* __restrict__ Xe)
{
    int row = blockIdx.x * 8 + (threadIdx.x >> 5);
    int i = threadIdx.x & 31;
    int tok = x[row];
    uint4 v = make_uint4(0, 0, 0, 0);
    if (i < 25) {
        const float* p = emb + (size_t)tok * 200 + i * 8;
        float4 f0 = *(const float4*)p;
        float4 f1 = *(const float4*)(p + 4);
        v.x = pack2(f0.x, f0.y); v.y = pack2(f0.z, f0.w);
        v.z = pack2(f1.x, f1.y); v.w = pack2(f1.z, f1.w);
    }
    *(uint4*)(Xe + (size_t)row * 256 + i * 8) = v;
}

// ---------------------------------------------------------------------------
// GEMM: OUT[M,N] = X[M,Kpad=256](bf16) @ W[N,K](fp32->bf16)^T + bias(fp32)
// block tile 128x128, 4 waves, wave = 64x64 (4x4 16x16x32 bf16 MFMA frags).
// ---------------------------------------------------------------------------
template <int OUT_F32>
__global__ __launch_bounds__(256) void k_gemm(const unsigned short* __restrict__ X, int ldx,
                                              const float* __restrict__ W, int K,
                                              const float* __restrict__ bias,
                                              unsigned short* __restrict__ outb,
                                              float* __restrict__ outf, int N)
{
    __shared__ __align__(16) unsigned short Al[128 * 72];
    __shared__ __align__(16) unsigned short Bl[128 * 72];
    const int tid = threadIdx.x, lane = tid & 63, wave = tid >> 6;
    const int wm = wave >> 1, wn = wave & 1;
    const int bm = blockIdx.y, bn = blockIdx.x;
    const int l15 = lane & 15, q = lane >> 4;

    f32x4 acc[4][4];
#pragma unroll
    for (int a = 0; a < 4; a++)
#pragma unroll
        for (int b = 0; b < 4; b++) acc[a][b] = f32x4{0.f, 0.f, 0.f, 0.f};

    for (int kb = 0; kb < 256; kb += 64) {
        __syncthreads();
#pragma unroll
        for (int it = 0; it < 4; ++it) {
            int p = tid + it * 256;
            int row = p >> 3, c8 = p & 7;
            int col = kb + c8 * 8;
            uint4 av = *(const uint4*)(X + (size_t)(bm * 128 + row) * ldx + col);
            *(uint4*)(Al + row * 72 + c8 * 8) = av;
            uint4 bv = make_uint4(0, 0, 0, 0);
            if (col < K) {
                const float* wp = W + (size_t)(bn * 128 + row) * K + col;
                float4 f0 = *(const float4*)wp;
                float4 f1 = *(const float4*)(wp + 4);
                bv.x = pack2(f0.x, f0.y); bv.y = pack2(f0.z, f0.w);
                bv.z = pack2(f1.x, f1.y); bv.w = pack2(f1.z, f1.w);
            }
            *(uint4*)(Bl + row * 72 + c8 * 8) = bv;
        }
        __syncthreads();
#pragma unroll
        for (int kt = 0; kt < 2; ++kt) {
            bf16x8 a[4], b[4];
#pragma unroll
            for (int mt = 0; mt < 4; ++mt)
                a[mt] = *(const bf16x8*)(Al + (wm * 64 + mt * 16 + l15) * 72 + kt * 32 + q * 8);
#pragma unroll
            for (int nt = 0; nt < 4; ++nt)
                b[nt] = *(const bf16x8*)(Bl + (wn * 64 + nt * 16 + l15) * 72 + kt * 32 + q * 8);
#pragma unroll
            for (int mt = 0; mt < 4; ++mt)
#pragma unroll
                for (int nt = 0; nt < 4; ++nt)
                    acc[mt][nt] = __builtin_amdgcn_mfma_f32_16x16x32_bf16(a[mt], b[nt], acc[mt][nt], 0, 0, 0);
        }
    }
#pragma unroll
    for (int nt = 0; nt < 4; ++nt) {
        int gn = bn * 128 + wn * 64 + nt * 16 + l15;
        float bv = bias[gn];
#pragma unroll
        for (int mt = 0; mt < 4; ++mt) {
#pragma unroll
            for (int r = 0; r < 4; ++r) {
                int gm = bm * 128 + wm * 64 + mt * 16 + q * 4 + r;
                float v = acc[mt][nt][r] + bv;
                if (OUT_F32) outf[(size_t)gm * N + gn] = v;
                else outb[(size_t)gm * N + gn] = f2bf(v);
            }
        }
    }
}

// ---------------------------------------------------------------------------
// LSTM recurrent scan, one layer. 16 WGs x 256 thr. WG s owns units
// [s*16,s*16+16). Wh slice in registers (B-frags hoisted). Per step:
// g[16b,64rows] = xg + h@Wh^T (MFMA M=16), cell update, h published as
// tagged u64 {tag:32 | 2xbf16:32} — single-hop relaxed-atomic exchange,
// no fence / no flags. tag = tagbase + t + 1 unique across layers.
// ---------------------------------------------------------------------------
__global__ __launch_bounds__(256) void k_scan(const float* __restrict__ Wh,           // [1024][256] fp32
                                              const unsigned short* __restrict__ xg,  // [4096][1024] bf16
                                              unsigned short* __restrict__ hseq,      // [4096][256] bf16
                                              unsigned long long* __restrict__ hglob, // [2][2048] u64
                                              unsigned tagbase)
{
    __shared__ __align__(16) unsigned short Wl[4 * 8 * 64 * 8];   // 32 KB staged weights
    __shared__ __align__(16) unsigned short hA[4096];             // 8 KB A-frag h[t-1]
    __shared__ float gbuf[64 * 17];
    const int tid = threadIdx.x, lane = tid & 63, wave = tid >> 6;
    const int s = blockIdx.x;
    const int l15 = lane & 15, q = lane >> 4;

    for (int p = tid; p < 2048; p += 256) {
        int nt = p >> 9, kt = (p >> 6) & 7, l = p & 63;
        int growp = nt * 256 + s * 16 + (l & 15);
        int k0 = kt * 32 + (l >> 4) * 8;
        const float* wp = Wh + (size_t)growp * 256 + k0;
        float4 f0 = *(const float4*)wp;
        float4 f1 = *(const float4*)(wp + 4);
        uint4 bv;
        bv.x = pack2(f0.x, f0.y); bv.y = pack2(f0.z, f0.w);
        bv.z = pack2(f1.x, f1.y); bv.w = pack2(f1.z, f1.w);
        *(uint4*)(Wl + ((nt * 8 + kt) * 64 + l) * 8) = bv;
    }
    const int eb = tid >> 4, eu = tid & 15;
    float c = 0.f;
    const int grow = wave * 256 + s * 16 + l15;   // this lane's gate-row
    __syncthreads();

    // hoist loop-invariant B-frags to registers (32 VGPRs)
    bf16x8 Breg[8];
#pragma unroll
    for (int kt = 0; kt < 8; ++kt)
        Breg[kt] = *(const bf16x8*)(Wl + ((wave * 8 + kt) * 64 + lane) * 8);

    // publish slot for this (even-eu) thread, A-frag u32 order
    const bool pub = (eu & 1) == 0;
    int slot;
    {
        int ug = s * 16 + eu;
        int kt = ug >> 5, qq = (ug >> 3) & 3, j = ug & 7;
        slot = ((kt * 64 + qq * 16 + eb) * 8 + j) >> 1;
    }
    unsigned* hA32 = (unsigned*)hA;

    for (int t = 0; t < 256; ++t) {
        // prefetch xg (bf16) for C-init — issued before the poll
        float x0 = __uint_as_float(((unsigned)xg[(size_t)((q * 4 + 0) * 256 + t) * 1024 + grow]) << 16);
        float x1 = __uint_as_float(((unsigned)xg[(size_t)((q * 4 + 1) * 256 + t) * 1024 + grow]) << 16);
        float x2 = __uint_as_float(((unsigned)xg[(size_t)((q * 4 + 2) * 256 + t) * 1024 + grow]) << 16);
        float x3 = __uint_as_float(((unsigned)xg[(size_t)((q * 4 + 3) * 256 + t) * 1024 + grow]) << 16);

        if (t > 0) {
            const unsigned long long* src = hglob + ((t - 1) & 1) * 2048 + tid;
            const unsigned expect = tagbase + (unsigned)t;
            unsigned long long v[8];
            unsigned pend = 0xffu;
            while (pend) {
#pragma unroll
                for (int i = 0; i < 8; ++i)
                    if (pend & (1u << i))
                        v[i] = __hip_atomic_load(src + i * 256, __ATOMIC_RELAXED,
                                                 __HIP_MEMORY_SCOPE_AGENT);
#pragma unroll
                for (int i = 0; i < 8; ++i)
                    if ((pend & (1u << i)) && (unsigned)(v[i] >> 32) == expect)
                        pend &= ~(1u << i);
            }
#pragma unroll
            for (int i = 0; i < 8; ++i) hA32[tid + i * 256] = (unsigned)v[i];
        } else {
#pragma unroll
            for (int i = 0; i < 8; ++i) hA32[tid + i * 256] = 0u;
        }
        __syncthreads();   // barrier A: hA staged (also fences gbuf read(t-1) vs write(t))

        f32x4 acc0 = {x0, x1, x2, x3};
        f32x4 acc1 = {0.f, 0.f, 0.f, 0.f};
#pragma unroll
        for (int kt = 0; kt < 8; kt += 2) {
            bf16x8 a0 = *(const bf16x8*)(hA + (kt * 64 + lane) * 8);
            acc0 = __builtin_amdgcn_mfma_f32_16x16x32_bf16(a0, Breg[kt], acc0, 0, 0, 0);
            bf16x8 a1 = *(const bf16x8*)(hA + ((kt + 1) * 64 + lane) * 8);
            acc1 = __builtin_amdgcn_mfma_f32_16x16x32_bf16(a1, Breg[kt + 1], acc1, 0, 0, 0);
        }
        {
            int rowb = wave * 16 + l15;
#pragma unroll
            for (int r = 0; r < 4; ++r) gbuf[rowb * 17 + q * 4 + r] = acc0[r] + acc1[r];
        }
        __syncthreads();   // barrier B: gbuf ready (also fences hA read(t) vs write(t+1))

        float gi = gbuf[(0 * 16 + eu) * 17 + eb];
        float gf = gbuf[(1 * 16 + eu) * 17 + eb];
        float gg = gbuf[(2 * 16 + eu) * 17 + eb];
        float go = gbuf[(3 * 16 + eu) * 17 + eb];
        float i_ = sigm(gi), f_ = sigm(gf), g_ = tanh_f(gg), o_ = sigm(go);
        c = f_ * c + i_ * g_;
        float h = o_ * tanh_f(c);
        float hn = __shfl_xor(h, 1);
        if (pub) {
            unsigned pk = pack2(h, hn);
            unsigned long long val =
                ((unsigned long long)(tagbase + (unsigned)t + 1u) << 32) | (unsigned long long)pk;
            __hip_atomic_store(hglob + (t & 1) * 2048 + slot, val, __ATOMIC_RELAXED,
                               __HIP_MEMORY_SCOPE_AGENT);
            *(unsigned*)(hseq + (size_t)(eb * 256 + t) * 256 + s * 16 + eu) = pk;
        }
    }
}

// ---------------------------------------------------------------------------
// Fused per-row logsumexp + subtract over V=32000 fp32 logits, row in regs.
// 1024 thr/WG, 32 f32 regs/thread; one read + one write of the logits.
// ---------------------------------------------------------------------------
__global__ __launch_bounds__(1024) void k_lsesub(float* __restrict__ lg)
{
    __shared__ float sm[16], ss[16];
    __shared__ float sL;
    const int row = blockIdx.x, tid = threadIdx.x;
    float* p = lg + (size_t)row * 32000;
    float4 v0[4], v1[4];
    float m = -3.0e38f, s = 0.f;
#pragma unroll
    for (int k = 0; k < 4; ++k) {
        int g = tid + (k << 10);
        if (g < 4000) {
            v0[k] = *(const float4*)(p + g * 8);
            v1[k] = *(const float4*)(p + g * 8 + 4);
            float a0 = fmaxf(fmaxf(v0[k].x, v0[k].y), fmaxf(v0[k].z, v0[k].w));
            float a1 = fmaxf(fmaxf(v1[k].x, v1[k].y), fmaxf(v1[k].z, v1[k].w));
            float ml = fmaxf(a0, a1);
            if (ml > m) { s *= __expf(m - ml); m = ml; }
            s += __expf(v0[k].x - m) + __expf(v0[k].y - m) + __expf(v0[k].z - m) + __expf(v0[k].w - m)
               + __expf(v1[k].x - m) + __expf(v1[k].y - m) + __expf(v1[k].z - m) + __expf(v1[k].w - m);
        }
    }
#pragma unroll
    for (int off = 32; off; off >>= 1) {
        float m2 = __shfl_xor(m, off);
        float s2 = __shfl_xor(s, off);
        float nm = fmaxf(m, m2);
        s = s * __expf(m - nm) + s2 * __expf(m2 - nm);
        m = nm;
    }
    if ((tid & 63) == 0) { sm[tid >> 6] = m; ss[tid >> 6] = s; }
    __syncthreads();
    if (tid == 0) {
        float M = sm[0], S = ss[0];
        for (int w = 1; w < 16; ++w) {
            float m2 = sm[w], s2 = ss[w];
            float nm = fmaxf(M, m2);
            S = S * __expf(M - nm) + s2 * __expf(m2 - nm);
            M = nm;
        }
        sL = M + __logf(S);
    }
    __syncthreads();
    const float L = sL;
#pragma unroll
    for (int k = 0; k < 4; ++k) {
        int g = tid + (k << 10);
        if (g < 4000) {
            v0[k].x -= L; v0[k].y -= L; v0[k].z -= L; v0[k].w -= L;
            v1[k].x -= L; v1[k].y -= L; v1[k].z -= L; v1[k].w -= L;
            *(float4*)(p + g * 8) = v0[k];
            *(float4*)(p + g * 8 + 4) = v1[k];
        }
    }
}

// ---------------------------------------------------------------------------
extern "C" void kernel_launch(void* const* d_in, const int* in_sizes, int n_in,
                              void* d_out, int out_size, void* d_ws, size_t ws_size,
                              hipStream_t stream)
{
    const int* x = (const int*)d_in[0];
    const float* emb = (const float*)d_in[1];
    const float* Wi0 = (const float*)d_in[2];
    const float* Wh0 = (const float*)d_in[3];
    const float* b0  = (const float*)d_in[4];
    const float* Wi1 = (const float*)d_in[5];
    const float* Wh1 = (const float*)d_in[6];
    const float* b1  = (const float*)d_in[7];
    const float* Wi2 = (const float*)d_in[8];
    const float* Wh2 = (const float*)d_in[9];
    const float* b2  = (const float*)d_in[10];
    const float* fcW = (const float*)d_in[11];
    const float* fcb = (const float*)d_in[12];
    float* out = (float*)d_out;

    uint8_t* w = (uint8_t*)d_ws;
    unsigned long long* hglob = (unsigned long long*)w;
    unsigned short* Xe = (unsigned short*)(w + OFF_XE);
    unsigned short* xg = (unsigned short*)(w + OFF_XG);
    unsigned short* hs = (unsigned short*)(w + OFF_HS);

    hipMemsetAsync(w, 0, 32768, stream);   // zero tagged h buffers

    k_embed<<<512, 256, 0, stream>>>(x, emb, Xe);

    k_gemm<0><<<dim3(8, 32), 256, 0, stream>>>(Xe, 256, Wi0, 200, b0, xg, nullptr, 1024);
    k_scan<<<16, 256, 0, stream>>>(Wh0, xg, hs, hglob, 0u);

    k_gemm<0><<<dim3(8, 32), 256, 0, stream>>>(hs, 256, Wi1, 256, b1, xg, nullptr, 1024);
    k_scan<<<16, 256, 0, stream>>>(Wh1, xg, hs, hglob, 256u);

    k_gemm<0><<<dim3(8, 32), 256, 0, stream>>>(hs, 256, Wi2, 256, b2, xg, nullptr, 1024);
    k_scan<<<16, 256, 0, stream>>>(Wh2, xg, hs, hglob, 512u);

    k_gemm<1><<<dim3(250, 32), 256, 0, stream>>>(hs, 256, fcW, 256, fcb, nullptr, out, 32000);

    k_lsesub<<<4096, 1024, 0, stream>>>(out);
}

// Round 3
// 1535.787 us; speedup vs baseline: 3.4283x; 1.5690x over previous
//
#include <hip/hip_runtime.h>
#include <stdint.h>

typedef __attribute__((ext_vector_type(8))) short bf16x8;
typedef __attribute__((ext_vector_type(4))) float f32x4;

#define DEV __device__ __forceinline__

DEV unsigned short f2bf(float f) {
    unsigned b = __float_as_uint(f);
    unsigned r = (b + 0x7fffu + ((b >> 16) & 1u)) >> 16;   // RNE
    return (unsigned short)r;
}
DEV unsigned pack2(float a, float b) {
    return (unsigned)f2bf(a) | ((unsigned)f2bf(b) << 16);
}
DEV bf16x8 pack8(float4 f0, float4 f1) {
    bf16x8 r;
    r[0] = (short)f2bf(f0.x); r[1] = (short)f2bf(f0.y);
    r[2] = (short)f2bf(f0.z); r[3] = (short)f2bf(f0.w);
    r[4] = (short)f2bf(f1.x); r[5] = (short)f2bf(f1.y);
    r[6] = (short)f2bf(f1.z); r[7] = (short)f2bf(f1.w);
    return r;
}
DEV float sigm(float x) { return 1.f / (1.f + __expf(-x)); }
DEV float tanh_f(float x) {
    float t = __expf(-2.f * fabsf(x));
    float r = (1.f - t) / (1.f + t);
    return copysignf(r, x);
}

// ws layout (bytes), total ~12.1 MB
// [0, 32768):  u64 ring2[2][2048]    layer-2 recurrent tagged ring
#define OFF_HB0   65536                       // 4 MB u64 Hb0[256][2048] (layer0 h, tagged)
#define OFF_HB1   (65536 + 4194304)           // 4 MB u64 Hb1[256][2048] (layer1 h, tagged)
#define OFF_XEA   (65536 + 8388608)           // 2 MB bf16 XeA[256][4096] (A-frag order)
#define OFF_HS    (OFF_XEA + 2097152)         // 2 MB bf16 hs[4096][256]  (layer2 h seq)

// ---------------------------------------------------------------------------
// Embedding gather + fp32->bf16, emitted directly in per-timestep A-frag
// order: XeA[t][(kt*64 + qq*16 + b)*8 + j] = bf16(emb[x[b*256+t]][kt*32+qq*8+j])
// ---------------------------------------------------------------------------
__global__ __launch_bounds__(256) void k_embed(const int* __restrict__ x,
                                               const float* __restrict__ emb,
                                               unsigned short* __restrict__ XeA)
{
    int row = blockIdx.x * 8 + (threadIdx.x >> 5);
    int i = threadIdx.x & 31;
    int tok = x[row];
    int b = row >> 8, t = row & 255;
    uint4 v = make_uint4(0, 0, 0, 0);
    if (i < 25) {
        const float* p = emb + (size_t)tok * 200 + i * 8;
        float4 f0 = *(const float4*)p;
        float4 f1 = *(const float4*)(p + 4);
        v.x = pack2(f0.x, f0.y); v.y = pack2(f0.z, f0.w);
        v.z = pack2(f1.x, f1.y); v.w = pack2(f1.z, f1.w);
    }
    int kt = i >> 2, qq = i & 3;
    *(uint4*)(XeA + (size_t)t * 4096 + (size_t)((kt * 64 + qq * 16 + b) * 8)) = v;
}

// ---------------------------------------------------------------------------
// GEMM: OUT[M,N] = X[M,Kpad=256](bf16) @ W[N,K](fp32->bf16)^T + bias(fp32)
// block tile 128x128, 4 waves, wave = 64x64 (4x4 16x16x32 bf16 MFMA frags).
// (used only for the final FC layer)
// ---------------------------------------------------------------------------
template <int OUT_F32>
__global__ __launch_bounds__(256) void k_gemm(const unsigned short* __restrict__ X, int ldx,
                                              const float* __restrict__ W, int K,
                                              const float* __restrict__ bias,
                                              unsigned short* __restrict__ outb,
                                              float* __restrict__ outf, int N)
{
    __shared__ __align__(16) unsigned short Al[128 * 72];
    __shared__ __align__(16) unsigned short Bl[128 * 72];
    const int tid = threadIdx.x, lane = tid & 63, wave = tid >> 6;
    const int wm = wave >> 1, wn = wave & 1;
    const int bm = blockIdx.y, bn = blockIdx.x;
    const int l15 = lane & 15, q = lane >> 4;

    f32x4 acc[4][4];
#pragma unroll
    for (int a = 0; a < 4; a++)
#pragma unroll
        for (int b = 0; b < 4; b++) acc[a][b] = f32x4{0.f, 0.f, 0.f, 0.f};

    for (int kb = 0; kb < 256; kb += 64) {
        __syncthreads();
#pragma unroll
        for (int it = 0; it < 4; ++it) {
            int p = tid + it * 256;
            int row = p >> 3, c8 = p & 7;
            int col = kb + c8 * 8;
            uint4 av = *(const uint4*)(X + (size_t)(bm * 128 + row) * ldx + col);
            *(uint4*)(Al + row * 72 + c8 * 8) = av;
            uint4 bv = make_uint4(0, 0, 0, 0);
            if (col < K) {
                const float* wp = W + (size_t)(bn * 128 + row) * K + col;
                float4 f0 = *(const float4*)wp;
                float4 f1 = *(const float4*)(wp + 4);
                bv.x = pack2(f0.x, f0.y); bv.y = pack2(f0.z, f0.w);
                bv.z = pack2(f1.x, f1.y); bv.w = pack2(f1.z, f1.w);
            }
            *(uint4*)(Bl + row * 72 + c8 * 8) = bv;
        }
        __syncthreads();
#pragma unroll
        for (int kt = 0; kt < 2; ++kt) {
            bf16x8 a[4], b[4];
#pragma unroll
            for (int mt = 0; mt < 4; ++mt)
                a[mt] = *(const bf16x8*)(Al + (wm * 64 + mt * 16 + l15) * 72 + kt * 32 + q * 8);
#pragma unroll
            for (int nt = 0; nt < 4; ++nt)
                b[nt] = *(const bf16x8*)(Bl + (wn * 64 + nt * 16 + l15) * 72 + kt * 32 + q * 8);
#pragma unroll
            for (int mt = 0; mt < 4; ++mt)
#pragma unroll
                for (int nt = 0; nt < 4; ++nt)
                    acc[mt][nt] = __builtin_amdgcn_mfma_f32_16x16x32_bf16(a[mt], b[nt], acc[mt][nt], 0, 0, 0);
        }
    }
#pragma unroll
    for (int nt = 0; nt < 4; ++nt) {
        int gn = bn * 128 + wn * 64 + nt * 16 + l15;
        float bv = bias[gn];
#pragma unroll
        for (int mt = 0; mt < 4; ++mt) {
#pragma unroll
            for (int r = 0; r < 4; ++r) {
                int gm = bm * 128 + wm * 64 + mt * 16 + q * 4 + r;
                float v = acc[mt][nt][r] + bv;
                if (OUT_F32) outf[(size_t)gm * N + gn] = v;
                else outb[(size_t)gm * N + gn] = f2bf(v);
            }
        }
    }
}

// ---------------------------------------------------------------------------
// Fused 3-layer LSTM scan with cross-layer pipelining. 48 WGs x 256 thr:
// WG (L,s) owns units [s*16,s*16+16) of layer L. Per step, each wave does
// 16 MFMAs (K=256 x-projection from layer below + K=256 recurrent), gates
// include bias. h published as tagged u64 {t+1:32 | 2xbf16:32}:
//   layers 0,1 -> full-sequence Hb[t] (write-once; feeds own t+1 AND layer
//   above at t), layer 2 -> 2-deep ring (progress-transitivity makes the
//   equality-tag check safe) + hs for the FC GEMM.
// Poll loops are s_sleep-throttled: a round with remaining pending words
// sleeps ~64 cy before retrying (bounds spin-issued MALL traffic).
// Critical path: 258 steps instead of 768.
// ---------------------------------------------------------------------------
__global__ __launch_bounds__(256) void k_scan3(
    const float* __restrict__ Wi0, const float* __restrict__ Wh0, const float* __restrict__ b0,
    const float* __restrict__ Wi1, const float* __restrict__ Wh1, const float* __restrict__ b1,
    const float* __restrict__ Wi2, const float* __restrict__ Wh2, const float* __restrict__ b2,
    const unsigned short* __restrict__ XeA,
    unsigned short* __restrict__ hseq,
    unsigned long long* __restrict__ Hb0,
    unsigned long long* __restrict__ Hb1,
    unsigned long long* __restrict__ ring2)
{
    __shared__ __align__(16) unsigned short hX[4096];   // x-source A-frags (16 x 256)
    __shared__ __align__(16) unsigned short hH[4096];   // h[t-1] A-frags
    __shared__ float gbuf[64 * 17];
    const int tid = threadIdx.x, lane = tid & 63, wave = tid >> 6;
    const int L = blockIdx.x >> 4, s = blockIdx.x & 15;
    const int l15 = lane & 15, q = lane >> 4;
    const int grow = wave * 256 + s * 16 + l15;          // gate-row (gate=wave)

    const float* Wi = (L == 0) ? Wi0 : ((L == 1) ? Wi1 : Wi2);
    const float* Wh = (L == 0) ? Wh0 : ((L == 1) ? Wh1 : Wh2);
    const float* bb = (L == 0) ? b0 : ((L == 1) ? b1 : b2);
    const int KX = (L == 0) ? 200 : 256;

    // loop-invariant weight B-frags in registers (64 VGPRs)
    bf16x8 WiR[8], WhR[8];
#pragma unroll
    for (int kt = 0; kt < 8; ++kt) {
        int k0 = kt * 32 + q * 8;
        {
            const float* p = Wh + (size_t)grow * 256 + k0;
            WhR[kt] = pack8(*(const float4*)p, *(const float4*)(p + 4));
        }
        if (k0 < KX) {
            const float* p = Wi + (size_t)grow * KX + k0;
            WiR[kt] = pack8(*(const float4*)p, *(const float4*)(p + 4));
        } else {
            WiR[kt] = bf16x8{0, 0, 0, 0, 0, 0, 0, 0};
        }
    }
    const float bv = bb[grow];

    const int eb = tid >> 4, eu = tid & 15;              // cell-update coords
    const bool pub = (eu & 1) == 0;
    int slot;
    {
        int ug = s * 16 + eu;
        int kt = ug >> 5, qq = (ug >> 3) & 3, j = ug & 7;
        slot = ((kt * 64 + qq * 16 + eb) * 8 + j) >> 1;
    }
    float c = 0.f;
    unsigned* hX32 = (unsigned*)hX;
    unsigned* hH32 = (unsigned*)hH;

    const unsigned long long* xbase = (L == 1) ? Hb0 : Hb1;   // unused for L==0
    unsigned long long* obase = (L == 0) ? Hb0 : Hb1;         // publish (L<2)
    const unsigned long long* rbase = (L == 0) ? Hb0 : Hb1;   // recurrent (L<2)

    for (int t = 0; t < 256; ++t) {
        if (L == 0) {   // x-source is precomputed embedding, direct coalesced copy
            const unsigned* srcx = (const unsigned*)(XeA + (size_t)t * 4096);
            *(uint4*)(hX32 + tid * 8)     = *(const uint4*)(srcx + tid * 8);
            *(uint4*)(hX32 + tid * 8 + 4) = *(const uint4*)(srcx + tid * 8 + 4);
        }
        {
            unsigned long long vx[8], vh[8];
            unsigned pendx = (L > 0) ? 0xffu : 0u;
            unsigned pendh = (t > 0) ? 0xffu : 0u;
            const unsigned long long* sx = xbase + (size_t)t * 2048 + tid;
            const unsigned long long* sh =
                (L == 2) ? (ring2 + ((t - 1) & 1) * 2048 + tid)
                         : (rbase + (size_t)((t > 0) ? (t - 1) : 0) * 2048 + tid);
            const unsigned ex = (unsigned)(t + 1), eh = (unsigned)t;
            while (pendx | pendh) {
#pragma unroll
                for (int i = 0; i < 8; ++i)
                    if (pendx & (1u << i))
                        vx[i] = __hip_atomic_load(sx + i * 256, __ATOMIC_RELAXED,
                                                  __HIP_MEMORY_SCOPE_AGENT);
#pragma unroll
                for (int i = 0; i < 8; ++i)
                    if (pendh & (1u << i))
                        vh[i] = __hip_atomic_load(sh + i * 256, __ATOMIC_RELAXED,
                                                  __HIP_MEMORY_SCOPE_AGENT);
#pragma unroll
                for (int i = 0; i < 8; ++i) {
                    if ((pendx & (1u << i)) && (unsigned)(vx[i] >> 32) == ex) pendx &= ~(1u << i);
                    if ((pendh & (1u << i)) && (unsigned)(vh[i] >> 32) == eh) pendh &= ~(1u << i);
                }
                if (pendx | pendh) __builtin_amdgcn_s_sleep(1);   // throttle spin
            }
            if (L > 0) {
#pragma unroll
                for (int i = 0; i < 8; ++i) hX32[tid + i * 256] = (unsigned)vx[i];
            }
            if (t > 0) {
#pragma unroll
                for (int i = 0; i < 8; ++i) hH32[tid + i * 256] = (unsigned)vh[i];
            } else {
#pragma unroll
                for (int i = 0; i < 8; ++i) hH32[tid + i * 256] = 0u;
            }
        }
        __syncthreads();   // barrier A: hX/hH staged

        f32x4 acc0 = {bv, bv, bv, bv};       // bias + x-projection
        f32x4 acc1 = {0.f, 0.f, 0.f, 0.f};   // recurrent
#pragma unroll
        for (int kt = 0; kt < 8; ++kt) {
            bf16x8 ax = *(const bf16x8*)(hX + (kt * 64 + lane) * 8);
            acc0 = __builtin_amdgcn_mfma_f32_16x16x32_bf16(ax, WiR[kt], acc0, 0, 0, 0);
            bf16x8 ah = *(const bf16x8*)(hH + (kt * 64 + lane) * 8);
            acc1 = __builtin_amdgcn_mfma_f32_16x16x32_bf16(ah, WhR[kt], acc1, 0, 0, 0);
        }
        {
            int rowb = wave * 16 + l15;
#pragma unroll
            for (int r = 0; r < 4; ++r) gbuf[rowb * 17 + q * 4 + r] = acc0[r] + acc1[r];
        }
        __syncthreads();   // barrier B: gbuf ready (also fences hX/hH reuse)

        float gi = gbuf[(0 * 16 + eu) * 17 + eb];
        float gf = gbuf[(1 * 16 + eu) * 17 + eb];
        float gg = gbuf[(2 * 16 + eu) * 17 + eb];
        float go = gbuf[(3 * 16 + eu) * 17 + eb];
        float i_ = sigm(gi), f_ = sigm(gf), g_ = tanh_f(gg), o_ = sigm(go);
        c = f_ * c + i_ * g_;
        float h = o_ * tanh_f(c);
        float hn = __shfl_xor(h, 1);
        if (pub) {
            unsigned pk = pack2(h, hn);
            unsigned long long val =
                ((unsigned long long)(unsigned)(t + 1) << 32) | (unsigned long long)pk;
            if (L == 2) {
                __hip_atomic_store(ring2 + (t & 1) * 2048 + slot, val, __ATOMIC_RELAXED,
                                   __HIP_MEMORY_SCOPE_AGENT);
                *(unsigned*)(hseq + (size_t)(eb * 256 + t) * 256 + s * 16 + eu) = pk;
            } else {
                __hip_atomic_store(obase + (size_t)t * 2048 + slot, val, __ATOMIC_RELAXED,
                                   __HIP_MEMORY_SCOPE_AGENT);
            }
        }
    }
}

// ---------------------------------------------------------------------------
// Fused per-row logsumexp + subtract over V=32000 fp32 logits, row in regs.
// ---------------------------------------------------------------------------
__global__ __launch_bounds__(1024) void k_lsesub(float* __restrict__ lg)
{
    __shared__ float sm[16], ss[16];
    __shared__ float sL;
    const int row = blockIdx.x, tid = threadIdx.x;
    float* p = lg + (size_t)row * 32000;
    float4 v0[4], v1[4];
    float m = -3.0e38f, s = 0.f;
#pragma unroll
    for (int k = 0; k < 4; ++k) {
        int g = tid + (k << 10);
        if (g < 4000) {
            v0[k] = *(const float4*)(p + g * 8);
            v1[k] = *(const float4*)(p + g * 8 + 4);
            float a0 = fmaxf(fmaxf(v0[k].x, v0[k].y), fmaxf(v0[k].z, v0[k].w));
            float a1 = fmaxf(fmaxf(v1[k].x, v1[k].y), fmaxf(v1[k].z, v1[k].w));
            float ml = fmaxf(a0, a1);
            if (ml > m) { s *= __expf(m - ml); m = ml; }
            s += __expf(v0[k].x - m) + __expf(v0[k].y - m) + __expf(v0[k].z - m) + __expf(v0[k].w - m)
               + __expf(v1[k].x - m) + __expf(v1[k].y - m) + __expf(v1[k].z - m) + __expf(v1[k].w - m);
        }
    }
#pragma unroll
    for (int off = 32; off; off >>= 1) {
        float m2 = __shfl_xor(m, off);
        float s2 = __shfl_xor(s, off);
        float nm = fmaxf(m, m2);
        s = s * __expf(m - nm) + s2 * __expf(m2 - nm);
        m = nm;
    }
    if ((tid & 63) == 0) { sm[tid >> 6] = m; ss[tid >> 6] = s; }
    __syncthreads();
    if (tid == 0) {
        float M = sm[0], S = ss[0];
        for (int w = 1; w < 16; ++w) {
            float m2 = sm[w], s2 = ss[w];
            float nm = fmaxf(M, m2);
            S = S * __expf(M - nm) + s2 * __expf(m2 - nm);
            M = nm;
        }
        sL = M + __logf(S);
    }
    __syncthreads();
    const float L = sL;
#pragma unroll
    for (int k = 0; k < 4; ++k) {
        int g = tid + (k << 10);
        if (g < 4000) {
            v0[k].x -= L; v0[k].y -= L; v0[k].z -= L; v0[k].w -= L;
            v1[k].x -= L; v1[k].y -= L; v1[k].z -= L; v1[k].w -= L;
            *(float4*)(p + g * 8) = v0[k];
            *(float4*)(p + g * 8 + 4) = v1[k];
        }
    }
}

// ---------------------------------------------------------------------------
extern "C" void kernel_launch(void* const* d_in, const int* in_sizes, int n_in,
                              void* d_out, int out_size, void* d_ws, size_t ws_size,
                              hipStream_t stream)
{
    const int* x = (const int*)d_in[0];
    const float* emb = (const float*)d_in[1];
    const float* Wi0 = (const float*)d_in[2];
    const float* Wh0 = (const float*)d_in[3];
    const float* b0  = (const float*)d_in[4];
    const float* Wi1 = (const float*)d_in[5];
    const float* Wh1 = (const float*)d_in[6];
    const float* b1  = (const float*)d_in[7];
    const float* Wi2 = (const float*)d_in[8];
    const float* Wh2 = (const float*)d_in[9];
    const float* b2  = (const float*)d_in[10];
    const float* fcW = (const float*)d_in[11];
    const float* fcb = (const float*)d_in[12];
    float* out = (float*)d_out;

    uint8_t* w = (uint8_t*)d_ws;
    unsigned long long* ring2 = (unsigned long long*)w;
    unsigned long long* Hb0 = (unsigned long long*)(w + OFF_HB0);
    unsigned long long* Hb1 = (unsigned long long*)(w + OFF_HB1);
    unsigned short* XeA = (unsigned short*)(w + OFF_XEA);
    unsigned short* hs  = (unsigned short*)(w + OFF_HS);

    hipMemsetAsync(w, 0, OFF_XEA, stream);   // zero ring2 + Hb0 + Hb1 tags

    k_embed<<<512, 256, 0, stream>>>(x, emb, XeA);

    k_scan3<<<48, 256, 0, stream>>>(Wi0, Wh0, b0, Wi1, Wh1, b1, Wi2, Wh2, b2,
                                    XeA, hs, Hb0, Hb1, ring2);

    k_gemm<1><<<dim3(250, 32), 256, 0, stream>>>(hs, 256, fcW, 256, fcb, nullptr, out, 32000);

    k_lsesub<<<4096, 1024, 0, stream>>>(out);
}

// Round 4
// 1534.177 us; speedup vs baseline: 3.4319x; 1.0010x over previous
//
#include <hip/hip_runtime.h>
#include <stdint.h>

typedef __attribute__((ext_vector_type(8))) short bf16x8;
typedef __attribute__((ext_vector_type(4))) float f32x4;

#define DEV __device__ __forceinline__

DEV unsigned short f2bf(float f) {
    unsigned b = __float_as_uint(f);
    unsigned r = (b + 0x7fffu + ((b >> 16) & 1u)) >> 16;   // RNE
    return (unsigned short)r;
}
DEV unsigned pack2(float a, float b) {
    return (unsigned)f2bf(a) | ((unsigned)f2bf(b) << 16);
}
DEV bf16x8 pack8(float4 f0, float4 f1) {
    bf16x8 r;
    r[0] = (short)f2bf(f0.x); r[1] = (short)f2bf(f0.y);
    r[2] = (short)f2bf(f0.z); r[3] = (short)f2bf(f0.w);
    r[4] = (short)f2bf(f1.x); r[5] = (short)f2bf(f1.y);
    r[6] = (short)f2bf(f1.z); r[7] = (short)f2bf(f1.w);
    return r;
}
DEV float sigm(float x) { return 1.f / (1.f + __expf(-x)); }
DEV float tanh_f(float x) {
    float t = __expf(-2.f * fabsf(x));
    float r = (1.f - t) / (1.f + t);
    return copysignf(r, x);
}

// ws layout (bytes)
// [0, 32768):  u64 ring2[2][2048]    layer-2 recurrent tagged ring
#define OFF_HB0   65536                       // 4 MB u64 Hb0[256][2048] (layer0 h, tagged)
#define OFF_HB1   (65536 + 4194304)           // 4 MB u64 Hb1[256][2048] (layer1 h, tagged)
#define OFF_XEA   (65536 + 8388608)           // 2 MB bf16 XeA[256][4096] (A-frag order)
#define OFF_HS    (OFF_XEA + 2097152)         // 2 MB bf16 hs[4096][256]  (layer2 h seq)
#define OFF_WB    (OFF_HS + 2097152)          // 16.4 MB bf16 Wb[32000][256] (fcW pre-converted)
#define WB_BYTES  (32000u * 256u * 2u)

// ---------------------------------------------------------------------------
// Embedding gather + fp32->bf16, emitted directly in per-timestep A-frag
// order: XeA[t][(kt*64 + qq*16 + b)*8 + j] = bf16(emb[x[b*256+t]][kt*32+qq*8+j])
// ---------------------------------------------------------------------------
__global__ __launch_bounds__(256) void k_embed(const int* __restrict__ x,
                                               const float* __restrict__ emb,
                                               unsigned short* __restrict__ XeA)
{
    int row = blockIdx.x * 8 + (threadIdx.x >> 5);
    int i = threadIdx.x & 31;
    int tok = x[row];
    int b = row >> 8, t = row & 255;
    uint4 v = make_uint4(0, 0, 0, 0);
    if (i < 25) {
        const float* p = emb + (size_t)tok * 200 + i * 8;
        float4 f0 = *(const float4*)p;
        float4 f1 = *(const float4*)(p + 4);
        v.x = pack2(f0.x, f0.y); v.y = pack2(f0.z, f0.w);
        v.z = pack2(f1.x, f1.y); v.w = pack2(f1.z, f1.w);
    }
    int kt = i >> 2, qq = i & 3;
    *(uint4*)(XeA + (size_t)t * 4096 + (size_t)((kt * 64 + qq * 16 + b) * 8)) = v;
}

// ---------------------------------------------------------------------------
// One-shot fcW fp32 -> bf16 pre-conversion (same RNE as in-GEMM convert)
// ---------------------------------------------------------------------------
__global__ __launch_bounds__(256) void k_wcvt(const float* __restrict__ W,
                                              unsigned short* __restrict__ Wb)
{
    size_t i = ((size_t)blockIdx.x * 256 + threadIdx.x) * 8;
    float4 f0 = *(const float4*)(W + i);
    float4 f1 = *(const float4*)(W + i + 4);
    uint4 v;
    v.x = pack2(f0.x, f0.y); v.y = pack2(f0.z, f0.w);
    v.z = pack2(f1.x, f1.y); v.w = pack2(f1.z, f1.w);
    *(uint4*)(Wb + i) = v;
}

// ---------------------------------------------------------------------------
// GEMM (fallback, fp32 W converted in-kernel):
// OUT[M,N] = X[M,Kpad=256](bf16) @ W[N,K](fp32->bf16)^T + bias(fp32)
// ---------------------------------------------------------------------------
template <int OUT_F32>
__global__ __launch_bounds__(256) void k_gemm(const unsigned short* __restrict__ X, int ldx,
                                              const float* __restrict__ W, int K,
                                              const float* __restrict__ bias,
                                              unsigned short* __restrict__ outb,
                                              float* __restrict__ outf, int N)
{
    __shared__ __align__(16) unsigned short Al[128 * 72];
    __shared__ __align__(16) unsigned short Bl[128 * 72];
    const int tid = threadIdx.x, lane = tid & 63, wave = tid >> 6;
    const int wm = wave >> 1, wn = wave & 1;
    const int bm = blockIdx.y, bn = blockIdx.x;
    const int l15 = lane & 15, q = lane >> 4;

    f32x4 acc[4][4];
#pragma unroll
    for (int a = 0; a < 4; a++)
#pragma unroll
        for (int b = 0; b < 4; b++) acc[a][b] = f32x4{0.f, 0.f, 0.f, 0.f};

    for (int kb = 0; kb < 256; kb += 64) {
        __syncthreads();
#pragma unroll
        for (int it = 0; it < 4; ++it) {
            int p = tid + it * 256;
            int row = p >> 3, c8 = p & 7;
            int col = kb + c8 * 8;
            uint4 av = *(const uint4*)(X + (size_t)(bm * 128 + row) * ldx + col);
            *(uint4*)(Al + row * 72 + c8 * 8) = av;
            uint4 bv = make_uint4(0, 0, 0, 0);
            if (col < K) {
                const float* wp = W + (size_t)(bn * 128 + row) * K + col;
                float4 f0 = *(const float4*)wp;
                float4 f1 = *(const float4*)(wp + 4);
                bv.x = pack2(f0.x, f0.y); bv.y = pack2(f0.z, f0.w);
                bv.z = pack2(f1.x, f1.y); bv.w = pack2(f1.z, f1.w);
            }
            *(uint4*)(Bl + row * 72 + c8 * 8) = bv;
        }
        __syncthreads();
#pragma unroll
        for (int kt = 0; kt < 2; ++kt) {
            bf16x8 a[4], b[4];
#pragma unroll
            for (int mt = 0; mt < 4; ++mt)
                a[mt] = *(const bf16x8*)(Al + (wm * 64 + mt * 16 + l15) * 72 + kt * 32 + q * 8);
#pragma unroll
            for (int nt = 0; nt < 4; ++nt)
                b[nt] = *(const bf16x8*)(Bl + (wn * 64 + nt * 16 + l15) * 72 + kt * 32 + q * 8);
#pragma unroll
            for (int mt = 0; mt < 4; ++mt)
#pragma unroll
                for (int nt = 0; nt < 4; ++nt)
                    acc[mt][nt] = __builtin_amdgcn_mfma_f32_16x16x32_bf16(a[mt], b[nt], acc[mt][nt], 0, 0, 0);
        }
    }
#pragma unroll
    for (int nt = 0; nt < 4; ++nt) {
        int gn = bn * 128 + wn * 64 + nt * 16 + l15;
        float bv = bias[gn];
#pragma unroll
        for (int mt = 0; mt < 4; ++mt) {
#pragma unroll
            for (int r = 0; r < 4; ++r) {
                int gm = bm * 128 + wm * 64 + mt * 16 + q * 4 + r;
                float v = acc[mt][nt][r] + bv;
                if (OUT_F32) outf[(size_t)gm * N + gn] = v;
                else outb[(size_t)gm * N + gn] = f2bf(v);
            }
        }
    }
}

// ---------------------------------------------------------------------------
// GEMM, both operands bf16 [.,256] (pre-converted W): pure-copy staging, no
// in-loop conversion. OUT fp32 [M,32000] + bias. Tile/epilogue identical to
// k_gemm. Used for the final FC layer.
// ---------------------------------------------------------------------------
__global__ __launch_bounds__(256) void k_gemm_bf16(const unsigned short* __restrict__ X,
                                                   const unsigned short* __restrict__ Wb,
                                                   const float* __restrict__ bias,
                                                   float* __restrict__ outf)
{
    __shared__ __align__(16) unsigned short Al[128 * 72];
    __shared__ __align__(16) unsigned short Bl[128 * 72];
    const int tid = threadIdx.x, lane = tid & 63, wave = tid >> 6;
    const int wm = wave >> 1, wn = wave & 1;
    const int bm = blockIdx.y, bn = blockIdx.x;
    const int l15 = lane & 15, q = lane >> 4;
    const int N = 32000;

    f32x4 acc[4][4];
#pragma unroll
    for (int a = 0; a < 4; a++)
#pragma unroll
        for (int b = 0; b < 4; b++) acc[a][b] = f32x4{0.f, 0.f, 0.f, 0.f};

    for (int kb = 0; kb < 256; kb += 64) {
        __syncthreads();
#pragma unroll
        for (int it = 0; it < 4; ++it) {
            int p = tid + it * 256;
            int row = p >> 3, c8 = p & 7;
            int col = kb + c8 * 8;
            uint4 av = *(const uint4*)(X + (size_t)(bm * 128 + row) * 256 + col);
            *(uint4*)(Al + row * 72 + c8 * 8) = av;
            uint4 bv = *(const uint4*)(Wb + (size_t)(bn * 128 + row) * 256 + col);
            *(uint4*)(Bl + row * 72 + c8 * 8) = bv;
        }
        __syncthreads();
#pragma unroll
        for (int kt = 0; kt < 2; ++kt) {
            bf16x8 a[4], b[4];
#pragma unroll
            for (int mt = 0; mt < 4; ++mt)
                a[mt] = *(const bf16x8*)(Al + (wm * 64 + mt * 16 + l15) * 72 + kt * 32 + q * 8);
#pragma unroll
            for (int nt = 0; nt < 4; ++nt)
                b[nt] = *(const bf16x8*)(Bl + (wn * 64 + nt * 16 + l15) * 72 + kt * 32 + q * 8);
#pragma unroll
            for (int mt = 0; mt < 4; ++mt)
#pragma unroll
                for (int nt = 0; nt < 4; ++nt)
                    acc[mt][nt] = __builtin_amdgcn_mfma_f32_16x16x32_bf16(a[mt], b[nt], acc[mt][nt], 0, 0, 0);
        }
    }
#pragma unroll
    for (int nt = 0; nt < 4; ++nt) {
        int gn = bn * 128 + wn * 64 + nt * 16 + l15;
        float bv = bias[gn];
#pragma unroll
        for (int mt = 0; mt < 4; ++mt) {
#pragma unroll
            for (int r = 0; r < 4; ++r) {
                int gm = bm * 128 + wm * 64 + mt * 16 + q * 4 + r;
                outf[(size_t)gm * N + gn] = acc[mt][nt][r] + bv;
            }
        }
    }
}

// ---------------------------------------------------------------------------
// Fused 3-layer LSTM scan with cross-layer pipelining. 48 WGs x 256 thr:
// WG (L,s) owns units [s*16,s*16+16) of layer L. Per step, each wave does
// 16 MFMAs (K=256 x-projection from layer below + K=256 recurrent), gates
// include bias. h published as tagged u64 {t+1:32 | 2xbf16:32}:
//   layers 0,1 -> full-sequence Hb[t] (write-once; feeds own t+1 AND layer
//   above at t), layer 2 -> 2-deep ring (progress-transitivity makes the
//   equality-tag check safe) + hs for the FC GEMM.
// Poll loops are s_sleep-throttled. Critical path: 258 steps instead of 768.
// ---------------------------------------------------------------------------
__global__ __launch_bounds__(256) void k_scan3(
    const float* __restrict__ Wi0, const float* __restrict__ Wh0, const float* __restrict__ b0,
    const float* __restrict__ Wi1, const float* __restrict__ Wh1, const float* __restrict__ b1,
    const float* __restrict__ Wi2, const float* __restrict__ Wh2, const float* __restrict__ b2,
    const unsigned short* __restrict__ XeA,
    unsigned short* __restrict__ hseq,
    unsigned long long* __restrict__ Hb0,
    unsigned long long* __restrict__ Hb1,
    unsigned long long* __restrict__ ring2)
{
    __shared__ __align__(16) unsigned short hX[4096];   // x-source A-frags (16 x 256)
    __shared__ __align__(16) unsigned short hH[4096];   // h[t-1] A-frags
    __shared__ float gbuf[64 * 17];
    const int tid = threadIdx.x, lane = tid & 63, wave = tid >> 6;
    const int L = blockIdx.x >> 4, s = blockIdx.x & 15;
    const int l15 = lane & 15, q = lane >> 4;
    const int grow = wave * 256 + s * 16 + l15;          // gate-row (gate=wave)

    const float* Wi = (L == 0) ? Wi0 : ((L == 1) ? Wi1 : Wi2);
    const float* Wh = (L == 0) ? Wh0 : ((L == 1) ? Wh1 : Wh2);
    const float* bb = (L == 0) ? b0 : ((L == 1) ? b1 : b2);
    const int KX = (L == 0) ? 200 : 256;

    // loop-invariant weight B-frags in registers (64 VGPRs)
    bf16x8 WiR[8], WhR[8];
#pragma unroll
    for (int kt = 0; kt < 8; ++kt) {
        int k0 = kt * 32 + q * 8;
        {
            const float* p = Wh + (size_t)grow * 256 + k0;
            WhR[kt] = pack8(*(const float4*)p, *(const float4*)(p + 4));
        }
        if (k0 < KX) {
            const float* p = Wi + (size_t)grow * KX + k0;
            WiR[kt] = pack8(*(const float4*)p, *(const float4*)(p + 4));
        } else {
            WiR[kt] = bf16x8{0, 0, 0, 0, 0, 0, 0, 0};
        }
    }
    const float bv = bb[grow];

    const int eb = tid >> 4, eu = tid & 15;              // cell-update coords
    const bool pub = (eu & 1) == 0;
    int slot;
    {
        int ug = s * 16 + eu;
        int kt = ug >> 5, qq = (ug >> 3) & 3, j = ug & 7;
        slot = ((kt * 64 + qq * 16 + eb) * 8 + j) >> 1;
    }
    float c = 0.f;
    unsigned* hX32 = (unsigned*)hX;
    unsigned* hH32 = (unsigned*)hH;

    const unsigned long long* xbase = (L == 1) ? Hb0 : Hb1;   // unused for L==0
    unsigned long long* obase = (L == 0) ? Hb0 : Hb1;         // publish (L<2)
    const unsigned long long* rbase = (L == 0) ? Hb0 : Hb1;   // recurrent (L<2)

    for (int t = 0; t < 256; ++t) {
        if (L == 0) {   // x-source is precomputed embedding, direct coalesced copy
            const unsigned* srcx = (const unsigned*)(XeA + (size_t)t * 4096);
            *(uint4*)(hX32 + tid * 8)     = *(const uint4*)(srcx + tid * 8);
            *(uint4*)(hX32 + tid * 8 + 4) = *(const uint4*)(srcx + tid * 8 + 4);
        }
        {
            unsigned long long vx[8], vh[8];
            unsigned pendx = (L > 0) ? 0xffu : 0u;
            unsigned pendh = (t > 0) ? 0xffu : 0u;
            const unsigned long long* sx = xbase + (size_t)t * 2048 + tid;
            const unsigned long long* sh =
                (L == 2) ? (ring2 + ((t - 1) & 1) * 2048 + tid)
                         : (rbase + (size_t)((t > 0) ? (t - 1) : 0) * 2048 + tid);
            const unsigned ex = (unsigned)(t + 1), eh = (unsigned)t;
            while (pendx | pendh) {
#pragma unroll
                for (int i = 0; i < 8; ++i)
                    if (pendx & (1u << i))
                        vx[i] = __hip_atomic_load(sx + i * 256, __ATOMIC_RELAXED,
                                                  __HIP_MEMORY_SCOPE_AGENT);
#pragma unroll
                for (int i = 0; i < 8; ++i)
                    if (pendh & (1u << i))
                        vh[i] = __hip_atomic_load(sh + i * 256, __ATOMIC_RELAXED,
                                                  __HIP_MEMORY_SCOPE_AGENT);
#pragma unroll
                for (int i = 0; i < 8; ++i) {
                    if ((pendx & (1u << i)) && (unsigned)(vx[i] >> 32) == ex) pendx &= ~(1u << i);
                    if ((pendh & (1u << i)) && (unsigned)(vh[i] >> 32) == eh) pendh &= ~(1u << i);
                }
                if (pendx | pendh) __builtin_amdgcn_s_sleep(1);   // throttle spin
            }
            if (L > 0) {
#pragma unroll
                for (int i = 0; i < 8; ++i) hX32[tid + i * 256] = (unsigned)vx[i];
            }
            if (t > 0) {
#pragma unroll
                for (int i = 0; i < 8; ++i) hH32[tid + i * 256] = (unsigned)vh[i];
            } else {
#pragma unroll
                for (int i = 0; i < 8; ++i) hH32[tid + i * 256] = 0u;
            }
        }
        __syncthreads();   // barrier A: hX/hH staged

        f32x4 acc0 = {bv, bv, bv, bv};       // bias + x-projection
        f32x4 acc1 = {0.f, 0.f, 0.f, 0.f};   // recurrent
#pragma unroll
        for (int kt = 0; kt < 8; ++kt) {
            bf16x8 ax = *(const bf16x8*)(hX + (kt * 64 + lane) * 8);
            acc0 = __builtin_amdgcn_mfma_f32_16x16x32_bf16(ax, WiR[kt], acc0, 0, 0, 0);
            bf16x8 ah = *(const bf16x8*)(hH + (kt * 64 + lane) * 8);
            acc1 = __builtin_amdgcn_mfma_f32_16x16x32_bf16(ah, WhR[kt], acc1, 0, 0, 0);
        }
        {
            int rowb = wave * 16 + l15;
#pragma unroll
            for (int r = 0; r < 4; ++r) gbuf[rowb * 17 + q * 4 + r] = acc0[r] + acc1[r];
        }
        __syncthreads();   // barrier B: gbuf ready (also fences hX/hH reuse)

        float gi = gbuf[(0 * 16 + eu) * 17 + eb];
        float gf = gbuf[(1 * 16 + eu) * 17 + eb];
        float gg = gbuf[(2 * 16 + eu) * 17 + eb];
        float go = gbuf[(3 * 16 + eu) * 17 + eb];
        float i_ = sigm(gi), f_ = sigm(gf), g_ = tanh_f(gg), o_ = sigm(go);
        c = f_ * c + i_ * g_;
        float h = o_ * tanh_f(c);
        float hn = __shfl_xor(h, 1);
        if (pub) {
            unsigned pk = pack2(h, hn);
            unsigned long long val =
                ((unsigned long long)(unsigned)(t + 1) << 32) | (unsigned long long)pk;
            if (L == 2) {
                __hip_atomic_store(ring2 + (t & 1) * 2048 + slot, val, __ATOMIC_RELAXED,
                                   __HIP_MEMORY_SCOPE_AGENT);
                *(unsigned*)(hseq + (size_t)(eb * 256 + t) * 256 + s * 16 + eu) = pk;
            } else {
                __hip_atomic_store(obase + (size_t)t * 2048 + slot, val, __ATOMIC_RELAXED,
                                   __HIP_MEMORY_SCOPE_AGENT);
            }
        }
    }
}

// ---------------------------------------------------------------------------
// Fused per-row logsumexp + subtract over V=32000 fp32 logits, row in regs.
// ---------------------------------------------------------------------------
__global__ __launch_bounds__(1024) void k_lsesub(float* __restrict__ lg)
{
    __shared__ float sm[16], ss[16];
    __shared__ float sL;
    const int row = blockIdx.x, tid = threadIdx.x;
    float* p = lg + (size_t)row * 32000;
    float4 v0[4], v1[4];
    float m = -3.0e38f, s = 0.f;
#pragma unroll
    for (int k = 0; k < 4; ++k) {
        int g = tid + (k << 10);
        if (g < 4000) {
            v0[k] = *(const float4*)(p + g * 8);
            v1[k] = *(const float4*)(p + g * 8 + 4);
            float a0 = fmaxf(fmaxf(v0[k].x, v0[k].y), fmaxf(v0[k].z, v0[k].w));
            float a1 = fmaxf(fmaxf(v1[k].x, v1[k].y), fmaxf(v1[k].z, v1[k].w));
            float ml = fmaxf(a0, a1);
            if (ml > m) { s *= __expf(m - ml); m = ml; }
            s += __expf(v0[k].x - m) + __expf(v0[k].y - m) + __expf(v0[k].z - m) + __expf(v0[k].w - m)
               + __expf(v1[k].x - m) + __expf(v1[k].y - m) + __expf(v1[k].z - m) + __expf(v1[k].w - m);
        }
    }
#pragma unroll
    for (int off = 32; off; off >>= 1) {
        float m2 = __shfl_xor(m, off);
        float s2 = __shfl_xor(s, off);
        float nm = fmaxf(m, m2);
        s = s * __expf(m - nm) + s2 * __expf(m2 - nm);
        m = nm;
    }
    if ((tid & 63) == 0) { sm[tid >> 6] = m; ss[tid >> 6] = s; }
    __syncthreads();
    if (tid == 0) {
        float M = sm[0], S = ss[0];
        for (int w = 1; w < 16; ++w) {
            float m2 = sm[w], s2 = ss[w];
            float nm = fmaxf(M, m2);
            S = S * __expf(M - nm) + s2 * __expf(m2 - nm);
            M = nm;
        }
        sL = M + __logf(S);
    }
    __syncthreads();
    const float L = sL;
#pragma unroll
    for (int k = 0; k < 4; ++k) {
        int g = tid + (k << 10);
        if (g < 4000) {
            v0[k].x -= L; v0[k].y -= L; v0[k].z -= L; v0[k].w -= L;
            v1[k].x -= L; v1[k].y -= L; v1[k].z -= L; v1[k].w -= L;
            *(float4*)(p + g * 8) = v0[k];
            *(float4*)(p + g * 8 + 4) = v1[k];
        }
    }
}

// ---------------------------------------------------------------------------
extern "C" void kernel_launch(void* const* d_in, const int* in_sizes, int n_in,
                              void* d_out, int out_size, void* d_ws, size_t ws_size,
                              hipStream_t stream)
{
    const int* x = (const int*)d_in[0];
    const float* emb = (const float*)d_in[1];
    const float* Wi0 = (const float*)d_in[2];
    const float* Wh0 = (const float*)d_in[3];
    const float* b0  = (const float*)d_in[4];
    const float* Wi1 = (const float*)d_in[5];
    const float* Wh1 = (const float*)d_in[6];
    const float* b1  = (const float*)d_in[7];
    const float* Wi2 = (const float*)d_in[8];
    const float* Wh2 = (const float*)d_in[9];
    const float* b2  = (const float*)d_in[10];
    const float* fcW = (const float*)d_in[11];
    const float* fcb = (const float*)d_in[12];
    float* out = (float*)d_out;

    uint8_t* w = (uint8_t*)d_ws;
    unsigned long long* ring2 = (unsigned long long*)w;
    unsigned long long* Hb0 = (unsigned long long*)(w + OFF_HB0);
    unsigned long long* Hb1 = (unsigned long long*)(w + OFF_HB1);
    unsigned short* XeA = (unsigned short*)(w + OFF_XEA);
    unsigned short* hs  = (unsigned short*)(w + OFF_HS);
    unsigned short* Wb  = (unsigned short*)(w + OFF_WB);
    const bool wb_ok = ws_size >= (size_t)OFF_WB + (size_t)WB_BYTES;

    hipMemsetAsync(w, 0, OFF_XEA, stream);   // zero ring2 + Hb0 + Hb1 tags

    if (wb_ok) k_wcvt<<<4000, 256, 0, stream>>>(fcW, Wb);

    k_embed<<<512, 256, 0, stream>>>(x, emb, XeA);

    k_scan3<<<48, 256, 0, stream>>>(Wi0, Wh0, b0, Wi1, Wh1, b1, Wi2, Wh2, b2,
                                    XeA, hs, Hb0, Hb1, ring2);

    if (wb_ok)
        k_gemm_bf16<<<dim3(250, 32), 256, 0, stream>>>(hs, Wb, fcb, out);
    else
        k_gemm<1><<<dim3(250, 32), 256, 0, stream>>>(hs, 256, fcW, 256, fcb, nullptr, out, 32000);

    k_lsesub<<<4096, 1024, 0, stream>>>(out);
}